// Round 2
// 129.177 us; speedup vs baseline: 1.0920x; 1.0920x over previous
//
#include <hip/hip_runtime.h>
#include <stdint.h>

#define NJOINT 17
#define H      512
#define W      512
#define HW     (H * W)
#define TOPK   30
#define SLABH  16
#define NSLAB  (H / SLABH)        // 32 slabs per joint
#define W4     (W / 4)            // 128 float4 per row
#define PSLOT  16                 // per-slab over-threshold key slots
#define JCAP   (NSLAB * PSLOT)    // 512 keys per joint (bitonic size)
#define LCAP   64                 // LDS staging cap per slab
#define THRESH 0.9995f            // E[over-T peaks/joint]=130 (-11 sigma to 30), per-slab E=4.1 (+6 sigma to 16)
#define FBCAP  HW                 // fallback peak buffer per joint (exact worst case)

typedef unsigned long long u64;

static __device__ __forceinline__ float4 f4max(float4 a, float4 b) {
    return make_float4(fmaxf(a.x,b.x), fmaxf(a.y,b.y), fmaxf(a.z,b.z), fmaxf(a.w,b.w));
}

// ---------------------------------------------------------------------------
// K1: 5x5 NMS per (joint, 512x16 slab) — separable rowmax5 (LDS) + colmax5.
// Phase-1 iteration i loads exactly the center float4 that phase-2 iteration
// i-1 needs (lr = rr+2, same column), so centers are cached in 8 registers
// and phase 2 touches no global memory. Peaks with value >= THRESH are
// compacted (LDS atomic) into this slab's fixed 16-slot segment, zero-padded
// (key 0 never selected). Overflow -> flag -> K2 exact fallback.
// Key = (float_bits(val)<<32) | ~idx: desc by value, ties -> lower index
// (exactly jax.lax.top_k order); keys globally unique.
// ---------------------------------------------------------------------------
__global__ __launch_bounds__(256) void nms_collect(const float* __restrict__ heat,
                                                   u64* __restrict__ buf,    // [NJOINT][JCAP]
                                                   int* __restrict__ flags)  // [NJOINT][NSLAB]
{
    __shared__ float4 sB[(SLABH + 4) * W4];   // rowmax5: 20*128 f4 = 40 KB
    __shared__ u64    listA[LCAP];
    __shared__ int    cntA;
    const int s  = blockIdx.x;                // slab
    const int j  = blockIdx.y;                // joint
    const int t  = threadIdx.x;
    const int r0 = s * SLABH;
    const float4* hj4 = (const float4*)(heat + (size_t)j * HW);

    if (t == 0) cntA = 0;

    float4 cenR[8];   // cached center rows for phase 2 (lr 2..17 == rr 0..15)

    // ---- phase 1: rowmax5 for rows r0-2 .. r0+17 (20 rows) ----
    #pragma unroll
    for (int i = 0; i < (SLABH + 4) * W4 / 256; ++i) {   // 10 chunks/thread
        int chunk = t + 256 * i;
        int lr = chunk >> 7;            // local row 0..19
        int c  = chunk & (W4 - 1);      // float4 col
        int gy = r0 + lr - 2;
        float4 rm;
        if (gy < 0 || gy >= H) {
            rm = make_float4(-INFINITY, -INFINITY, -INFINITY, -INFINITY);
        } else {
            const float4* row = hj4 + (size_t)gy * W4;
            float4 Cv = row[c];
            if (i >= 1 && i <= 8) cenR[i - 1] = Cv;      // center for phase-2 iter i-1
            float Lz = -INFINITY, Lw = -INFINITY, Rx = -INFINITY, Ry = -INFINITY;
            if (c > 0)      { float4 Lv = row[c - 1]; Lz = Lv.z; Lw = Lv.w; }
            if (c < W4 - 1) { float4 Rv = row[c + 1]; Rx = Rv.x; Ry = Rv.y; }
            float mCxy = fmaxf(Cv.x, Cv.y);
            float mCzw = fmaxf(Cv.z, Cv.w);
            float mCyz = fmaxf(Cv.y, Cv.z);
            rm.x = fmaxf(fmaxf(Lz, Lw), fmaxf(mCxy, Cv.z));          // x-2..x+2
            rm.y = fmaxf(Lw, fmaxf(mCxy, mCzw));                     // x-1..x+3
            rm.z = fmaxf(fmaxf(mCxy, mCzw), Rx);                     // x..x+4
            rm.w = fmaxf(mCyz, fmaxf(Cv.w, fmaxf(Rx, Ry)));          // x+1..x+5
        }
        sB[lr * W4 + c] = rm;
    }
    __syncthreads();

    // ---- phase 2: colmax5 + peak test + threshold filter + compaction ----
    #pragma unroll
    for (int i = 0; i < SLABH * W4 / 256; ++i) {         // 8 chunks/thread
        int chunk = t + 256 * i;
        int rr = chunk >> 7;            // slab row 0..15
        int c  = chunk & (W4 - 1);
        int gy = r0 + rr;
        float4 cen = cenR[i];           // == hj4[gy*W4 + c], cached in phase 1
        const float4* b = &sB[rr * W4 + c];
        float4 m = b[0];
        m = f4max(m, b[1 * W4]);
        m = f4max(m, b[2 * W4]);
        m = f4max(m, b[3 * W4]);
        m = f4max(m, b[4 * W4]);
        unsigned base_idx = (unsigned)(gy * W + 4 * c);
        if (cen.x >= m.x && cen.x >= THRESH) { int p = atomicAdd(&cntA, 1); if (p < LCAP) listA[p] = ((u64)__float_as_uint(cen.x) << 32) | (u64)(~(base_idx + 0)); }
        if (cen.y >= m.y && cen.y >= THRESH) { int p = atomicAdd(&cntA, 1); if (p < LCAP) listA[p] = ((u64)__float_as_uint(cen.y) << 32) | (u64)(~(base_idx + 1)); }
        if (cen.z >= m.z && cen.z >= THRESH) { int p = atomicAdd(&cntA, 1); if (p < LCAP) listA[p] = ((u64)__float_as_uint(cen.z) << 32) | (u64)(~(base_idx + 2)); }
        if (cen.w >= m.w && cen.w >= THRESH) { int p = atomicAdd(&cntA, 1); if (p < LCAP) listA[p] = ((u64)__float_as_uint(cen.w) << 32) | (u64)(~(base_idx + 3)); }
    }
    __syncthreads();
    int c = cntA;
    if (t < PSLOT) buf[(size_t)j * JCAP + s * PSLOT + t] = (t < c) ? listA[t] : 0ull;
    if (t == 0)    flags[j * NSLAB + s] = (c > PSLOT) ? 1 : 0;
}

// ---------------------------------------------------------------------------
// K2: per joint — bitonic sort (descending) of the 512 slot keys in LDS.
// Direct pair indexing: thread q handles pair (i, i|jj) with
// i = ((q&~(jj-1))<<1)|(q&(jj-1)) — exactly 256 compare-exchanges per
// stage, no wasted strided iterations, half the LDS traffic of the p=i^jj
// guarded form. __syncthreads() after EVERY stage (memory-model safe: the
// compiler may not reorder cross-lane LDS RAW across a barrier; barrier-free
// wave-local stages are UNSAFE — hipcc hoists next-stage ds_read above
// prev-stage ds_write since they don't alias per-lane. Proven by the R1
// failure, absmax 560).
// Then validity check (no slab overflow, >=30 real keys), exact fallback
// otherwise (never taken for this data), then the heat_xy epilogue with
// numpy-matched rounding (add_rn then mul_rn, no contraction).
// ---------------------------------------------------------------------------
__global__ __launch_bounds__(256) void topk_sort(const u64* __restrict__ buf,
                                                 const int* __restrict__ flags,
                                                 const float* __restrict__ heat,
                                                 const float* __restrict__ offs,
                                                 const int* __restrict__ stride_p,
                                                 u64* __restrict__ fb,       // [NJOINT][FBCAP]
                                                 float* __restrict__ heat_xy)
{
    const int j = blockIdx.x, t = threadIdx.x;
    __shared__ u64 sk[JCAP];
    __shared__ int s_ovf;
    if (t == 0) s_ovf = 0;
    __syncthreads();
    if (t < NSLAB && flags[j * NSLAB + t]) atomicOr(&s_ovf, 1);
    for (int i = t; i < JCAP; i += 256) sk[i] = buf[(size_t)j * JCAP + i];
    __syncthreads();

    // bitonic sort, descending, N = 512; barrier per stage
    for (int kk = 2; kk <= JCAP; kk <<= 1) {
        for (int jj = kk >> 1; jj > 0; jj >>= 1) {
            int i = ((t & ~(jj - 1)) << 1) | (t & (jj - 1));
            int p = i | jj;
            u64 a = sk[i], b = sk[p];
            bool up = ((i & kk) == 0);       // descending region
            if (up ? (a < b) : (a > b)) { sk[i] = b; sk[p] = a; }
            __syncthreads();
        }
    }

    bool ok = (s_ovf == 0) && (sk[TOPK - 1] != 0);

    if (!ok) {
        // -------- exact fallback (adversarial data only; never taken here) --------
        __shared__ int fcnt;
        __shared__ u64 wred[4];
        __shared__ u64 s_prev;
        if (t == 0) fcnt = 0;
        __syncthreads();
        const float* hj = heat + (size_t)j * HW;
        u64* fj = fb + (size_t)j * FBCAP;
        for (int p0 = t; p0 < HW; p0 += 256) {
            int y = p0 >> 9, x = p0 & (W - 1);
            float cv = hj[p0];
            float m = -INFINITY;
            for (int dy = -2; dy <= 2; ++dy) {
                int yy = y + dy; if (yy < 0 || yy >= H) continue;
                for (int dx = -2; dx <= 2; ++dx) {
                    int xx = x + dx; if (xx < 0 || xx >= W) continue;
                    m = fmaxf(m, hj[yy * W + xx]);
                }
            }
            if (cv >= m) {
                int p = atomicAdd(&fcnt, 1);
                if (p < FBCAP) fj[p] = ((u64)__float_as_uint(cv) << 32) | (u64)(~(unsigned)p0);
            }
        }
        __syncthreads();
        int n = min(fcnt, FBCAP);
        u64 prev = ~0ull;
        for (int r = 0; r < TOPK; ++r) {
            u64 best = 0;
            for (int i = t; i < n; i += 256) {
                u64 k = fj[i];
                if (k < prev && k > best) best = k;
            }
            #pragma unroll
            for (int off = 32; off > 0; off >>= 1) {
                u64 o = __shfl_down(best, off);
                if (o > best) best = o;
            }
            if ((t & 63) == 0) wred[t >> 6] = best;
            __syncthreads();
            if (t == 0) {
                u64 b = wred[0];
                for (int w = 1; w < 4; ++w) if (wred[w] > b) b = wred[w];
                sk[r] = b; s_prev = b;
            }
            __syncthreads();
            prev = s_prev;
        }
    }

    if (t < TOPK) {
        u64 k = sk[t];
        float hx = 0.0f, hy = 0.0f;
        if (k != 0) {
            unsigned idx = ~(unsigned)(k & 0xFFFFFFFFull);
            int xi = (int)(idx & (W - 1));
            int yi = (int)(idx >> 9);
            float offx = offs[((size_t)j * 2 + 0) * HW + idx];
            float offy = offs[((size_t)j * 2 + 1) * HW + idx];
            float sf = (float)(*stride_p);
            hx = __fmul_rn(sf, __fadd_rn((float)xi, offx));
            hy = __fmul_rn(sf, __fadd_rn((float)yi, offy));
        }
        heat_xy[(j * TOPK + t) * 2 + 0] = hx;
        heat_xy[(j * TOPK + t) * 2 + 1] = hy;
    }
}

// ---------------------------------------------------------------------------
// K3: nearest-candidate snap. Pose flat index == 2*tid floats -> perfect
// float2 coalescing. Argmin runs on d^2 (no per-candidate sqrt): sqrt_rn is
// monotone non-decreasing, so first-argmin over sqrt(d2) equals first-argmin
// over d2 UNLESS a strictly-larger d2 rounds to the same sqrt as the
// minimum. Track min d2 (first index, strict <, matching jnp.argmin tie
// rule) AND the second-distinct min b2; 2 sqrts at the end certify: every
// other candidate has d2 >= b2, so sqrt(b2) > sqrt(bd) proves no sqrt-image
// tie anywhere (including at earlier indices). On collision (~1e-6/pose)
// fall back to the exact per-candidate sqrt scan (bitwise reference
// semantics). Saves ~28 correctly-rounded sqrt sequences (~10 VALU each)
// per thread.
// ---------------------------------------------------------------------------
__global__ __launch_bounds__(256) void assign_nearest(const float2* __restrict__ poses,
                                                      const float2* __restrict__ hxy,
                                                      float2* __restrict__ out,
                                                      int NJ)
{
    __shared__ float2 cand[NJOINT * TOPK];
    const int t = threadIdx.x;
    for (int i = t; i < NJOINT * TOPK; i += 256) cand[i] = hxy[i];
    __syncthreads();
    int tid = blockIdx.x * 256 + t;
    if (tid >= NJ) return;
    int j = tid % NJOINT;
    float2 p = poses[tid];
    float bd = INFINITY;   // min d2 (first index wins, strict <)
    float b2 = INFINITY;   // smallest d2 value strictly greater than bd
    int   bk = 0;
    #pragma unroll
    for (int k = 0; k < TOPK; ++k) {
        float2 c  = cand[j * TOPK + k];
        float  dx = __fsub_rn(p.x, c.x);
        float  dy = __fsub_rn(p.y, c.y);
        float  d2 = __fadd_rn(__fmul_rn(dx, dx), __fmul_rn(dy, dy));
        if (d2 < bd)                    { b2 = bd; bd = d2; bk = k; }
        else if (d2 < b2 && d2 > bd)    { b2 = d2; }
    }
    float smin = __fsqrt_rn(bd);
    if (__fsqrt_rn(b2) == smin) {
        // rounding collision: replicate the reference scan exactly (rare)
        float bs = INFINITY; bk = 0;
        for (int k = 0; k < TOPK; ++k) {
            float2 c  = cand[j * TOPK + k];
            float  dx = __fsub_rn(p.x, c.x);
            float  dy = __fsub_rn(p.y, c.y);
            float  s  = __fsqrt_rn(__fadd_rn(__fmul_rn(dx, dx), __fmul_rn(dy, dy)));
            if (s < bs) { bs = s; bk = k; }
        }
    }
    out[tid] = cand[j * TOPK + bk];
}

extern "C" void kernel_launch(void* const* d_in, const int* in_sizes, int n_in,
                              void* d_out, int out_size, void* d_ws, size_t ws_size,
                              hipStream_t stream)
{
    const float* poses    = (const float*)d_in[0];   // (N, 34)
    const float* heat     = (const float*)d_in[1];   // (17, 512, 512)
    const float* offs     = (const float*)d_in[2];   // (17, 2, 512, 512)
    const int*   stride_p = (const int*)d_in[3];     // scalar 4

    char* ws = (char*)d_ws;
    u64*   buf     = (u64*)ws;                                   // 17*512*8   = 69,632 B
    int*   flags   = (int*)(ws + (size_t)NJOINT * JCAP * 8);     // 17*32*4    = 2,176 B
    float* heat_xy = (float*)(ws + (size_t)NJOINT * JCAP * 8 + NJOINT * NSLAB * 4); // 4,080 B
    u64*   fb      = (u64*)(ws + (1 << 20));                     // fallback scratch @1 MiB, 35.7 MB

    dim3 g1(NSLAB, NJOINT, 1);
    nms_collect<<<g1, 256, 0, stream>>>(heat, buf, flags);

    topk_sort<<<NJOINT, 256, 0, stream>>>(buf, flags, heat, offs, stride_p, fb, heat_xy);

    int NJ = (in_sizes[0] / (2 * NJOINT)) * NJOINT;  // 100000 * 17
    assign_nearest<<<(NJ + 255) / 256, 256, 0, stream>>>(
        (const float2*)poses, (const float2*)heat_xy, (float2*)d_out, NJ);
}

// Round 3
// 125.798 us; speedup vs baseline: 1.1213x; 1.0269x over previous
//
#include <hip/hip_runtime.h>
#include <stdint.h>

#define NJOINT 17
#define H      512
#define W      512
#define HW     (H * W)
#define TOPK   30
#define SLABH  16
#define NSLAB  (H / SLABH)        // 32 slabs per joint
#define W4     (W / 4)            // 128 float4 per row
#define PSLOT  16                 // per-slab over-threshold key slots
#define JCAP   (NSLAB * PSLOT)    // 512 keys per joint (bitonic size)
#define LCAP   64                 // LDS staging cap per slab
#define THRESH 0.9995f            // E[over-T peaks/joint]=130 (-11 sigma to 30), per-slab E=4.1 (+6 sigma to 16)
#define FBCAP  HW                 // fallback peak buffer per joint (exact worst case)
#define CSTRIDE 33                // cand LDS row stride: bank=(2j+2k)%32 -> max 2-way (free)

typedef unsigned long long u64;

static __device__ __forceinline__ float4 f4max(float4 a, float4 b) {
    return make_float4(fmaxf(a.x,b.x), fmaxf(a.y,b.y), fmaxf(a.z,b.z), fmaxf(a.w,b.w));
}

// ---------------------------------------------------------------------------
// K1: 5x5 NMS per (joint, 512x16 slab) — separable rowmax5 (LDS) + colmax5.
// Phase-1 iteration i loads exactly the center float4 that phase-2 iteration
// i-1 needs (lr = rr+2, same column), so centers are cached in 8 registers
// and phase 2 touches no global memory. Peaks with value >= THRESH are
// compacted (LDS atomic) into this slab's fixed 16-slot segment, zero-padded
// (key 0 never selected). Overflow -> flag -> K2 exact fallback.
// Key = (float_bits(val)<<32) | ~idx: desc by value, ties -> lower index
// (exactly jax.lax.top_k order); keys globally unique.
// ---------------------------------------------------------------------------
__global__ __launch_bounds__(256) void nms_collect(const float* __restrict__ heat,
                                                   u64* __restrict__ buf,    // [NJOINT][JCAP]
                                                   int* __restrict__ flags)  // [NJOINT][NSLAB]
{
    __shared__ float4 sB[(SLABH + 4) * W4];   // rowmax5: 20*128 f4 = 40 KB
    __shared__ u64    listA[LCAP];
    __shared__ int    cntA;
    const int s  = blockIdx.x;                // slab
    const int j  = blockIdx.y;                // joint
    const int t  = threadIdx.x;
    const int r0 = s * SLABH;
    const float4* hj4 = (const float4*)(heat + (size_t)j * HW);

    if (t == 0) cntA = 0;

    float4 cenR[8];   // cached center rows for phase 2 (lr 2..17 == rr 0..15)

    // ---- phase 1: rowmax5 for rows r0-2 .. r0+17 (20 rows) ----
    #pragma unroll
    for (int i = 0; i < (SLABH + 4) * W4 / 256; ++i) {   // 10 chunks/thread
        int chunk = t + 256 * i;
        int lr = chunk >> 7;            // local row 0..19
        int c  = chunk & (W4 - 1);      // float4 col
        int gy = r0 + lr - 2;
        float4 rm;
        if (gy < 0 || gy >= H) {
            rm = make_float4(-INFINITY, -INFINITY, -INFINITY, -INFINITY);
        } else {
            const float4* row = hj4 + (size_t)gy * W4;
            float4 Cv = row[c];
            if (i >= 1 && i <= 8) cenR[i - 1] = Cv;      // center for phase-2 iter i-1
            float Lz = -INFINITY, Lw = -INFINITY, Rx = -INFINITY, Ry = -INFINITY;
            if (c > 0)      { float4 Lv = row[c - 1]; Lz = Lv.z; Lw = Lv.w; }
            if (c < W4 - 1) { float4 Rv = row[c + 1]; Rx = Rv.x; Ry = Rv.y; }
            float mCxy = fmaxf(Cv.x, Cv.y);
            float mCzw = fmaxf(Cv.z, Cv.w);
            float mCyz = fmaxf(Cv.y, Cv.z);
            rm.x = fmaxf(fmaxf(Lz, Lw), fmaxf(mCxy, Cv.z));          // x-2..x+2
            rm.y = fmaxf(Lw, fmaxf(mCxy, mCzw));                     // x-1..x+3
            rm.z = fmaxf(fmaxf(mCxy, mCzw), Rx);                     // x..x+4
            rm.w = fmaxf(mCyz, fmaxf(Cv.w, fmaxf(Rx, Ry)));          // x+1..x+5
        }
        sB[lr * W4 + c] = rm;
    }
    __syncthreads();

    // ---- phase 2: colmax5 + peak test + threshold filter + compaction ----
    #pragma unroll
    for (int i = 0; i < SLABH * W4 / 256; ++i) {         // 8 chunks/thread
        int chunk = t + 256 * i;
        int rr = chunk >> 7;            // slab row 0..15
        int c  = chunk & (W4 - 1);
        int gy = r0 + rr;
        float4 cen = cenR[i];           // == hj4[gy*W4 + c], cached in phase 1
        const float4* b = &sB[rr * W4 + c];
        float4 m = b[0];
        m = f4max(m, b[1 * W4]);
        m = f4max(m, b[2 * W4]);
        m = f4max(m, b[3 * W4]);
        m = f4max(m, b[4 * W4]);
        unsigned base_idx = (unsigned)(gy * W + 4 * c);
        if (cen.x >= m.x && cen.x >= THRESH) { int p = atomicAdd(&cntA, 1); if (p < LCAP) listA[p] = ((u64)__float_as_uint(cen.x) << 32) | (u64)(~(base_idx + 0)); }
        if (cen.y >= m.y && cen.y >= THRESH) { int p = atomicAdd(&cntA, 1); if (p < LCAP) listA[p] = ((u64)__float_as_uint(cen.y) << 32) | (u64)(~(base_idx + 1)); }
        if (cen.z >= m.z && cen.z >= THRESH) { int p = atomicAdd(&cntA, 1); if (p < LCAP) listA[p] = ((u64)__float_as_uint(cen.z) << 32) | (u64)(~(base_idx + 2)); }
        if (cen.w >= m.w && cen.w >= THRESH) { int p = atomicAdd(&cntA, 1); if (p < LCAP) listA[p] = ((u64)__float_as_uint(cen.w) << 32) | (u64)(~(base_idx + 3)); }
    }
    __syncthreads();
    int c = cntA;
    if (t < PSLOT) buf[(size_t)j * JCAP + s * PSLOT + t] = (t < c) ? listA[t] : 0ull;
    if (t == 0)    flags[j * NSLAB + s] = (c > PSLOT) ? 1 : 0;
}

// ---------------------------------------------------------------------------
// K2: per joint — bitonic sort (descending) of the 512 slot keys in LDS.
// Direct pair indexing: thread q handles pair (i, i|jj) with
// i = ((q&~(jj-1))<<1)|(q&(jj-1)) — exactly 256 compare-exchanges per
// stage. __syncthreads() after EVERY stage (memory-model safe; barrier-free
// wave-local stages are UNSAFE — hipcc hoists next-stage ds_read above
// prev-stage ds_write since they don't alias per-lane; proven by R1 failure).
// Then validity check, exact fallback otherwise (never taken for this data),
// then the heat_xy epilogue with numpy-matched rounding.
// ---------------------------------------------------------------------------
__global__ __launch_bounds__(256) void topk_sort(const u64* __restrict__ buf,
                                                 const int* __restrict__ flags,
                                                 const float* __restrict__ heat,
                                                 const float* __restrict__ offs,
                                                 const int* __restrict__ stride_p,
                                                 u64* __restrict__ fb,       // [NJOINT][FBCAP]
                                                 float* __restrict__ heat_xy)
{
    const int j = blockIdx.x, t = threadIdx.x;
    __shared__ u64 sk[JCAP];
    __shared__ int s_ovf;
    if (t == 0) s_ovf = 0;
    __syncthreads();
    if (t < NSLAB && flags[j * NSLAB + t]) atomicOr(&s_ovf, 1);
    for (int i = t; i < JCAP; i += 256) sk[i] = buf[(size_t)j * JCAP + i];
    __syncthreads();

    // bitonic sort, descending, N = 512; barrier per stage
    for (int kk = 2; kk <= JCAP; kk <<= 1) {
        for (int jj = kk >> 1; jj > 0; jj >>= 1) {
            int i = ((t & ~(jj - 1)) << 1) | (t & (jj - 1));
            int p = i | jj;
            u64 a = sk[i], b = sk[p];
            bool up = ((i & kk) == 0);       // descending region
            if (up ? (a < b) : (a > b)) { sk[i] = b; sk[p] = a; }
            __syncthreads();
        }
    }

    bool ok = (s_ovf == 0) && (sk[TOPK - 1] != 0);

    if (!ok) {
        // -------- exact fallback (adversarial data only; never taken here) --------
        __shared__ int fcnt;
        __shared__ u64 wred[4];
        __shared__ u64 s_prev;
        if (t == 0) fcnt = 0;
        __syncthreads();
        const float* hj = heat + (size_t)j * HW;
        u64* fj = fb + (size_t)j * FBCAP;
        for (int p0 = t; p0 < HW; p0 += 256) {
            int y = p0 >> 9, x = p0 & (W - 1);
            float cv = hj[p0];
            float m = -INFINITY;
            for (int dy = -2; dy <= 2; ++dy) {
                int yy = y + dy; if (yy < 0 || yy >= H) continue;
                for (int dx = -2; dx <= 2; ++dx) {
                    int xx = x + dx; if (xx < 0 || xx >= W) continue;
                    m = fmaxf(m, hj[yy * W + xx]);
                }
            }
            if (cv >= m) {
                int p = atomicAdd(&fcnt, 1);
                if (p < FBCAP) fj[p] = ((u64)__float_as_uint(cv) << 32) | (u64)(~(unsigned)p0);
            }
        }
        __syncthreads();
        int n = min(fcnt, FBCAP);
        u64 prev = ~0ull;
        for (int r = 0; r < TOPK; ++r) {
            u64 best = 0;
            for (int i = t; i < n; i += 256) {
                u64 k = fj[i];
                if (k < prev && k > best) best = k;
            }
            #pragma unroll
            for (int off = 32; off > 0; off >>= 1) {
                u64 o = __shfl_down(best, off);
                if (o > best) best = o;
            }
            if ((t & 63) == 0) wred[t >> 6] = best;
            __syncthreads();
            if (t == 0) {
                u64 b = wred[0];
                for (int w = 1; w < 4; ++w) if (wred[w] > b) b = wred[w];
                sk[r] = b; s_prev = b;
            }
            __syncthreads();
            prev = s_prev;
        }
    }

    if (t < TOPK) {
        u64 k = sk[t];
        float hx = 0.0f, hy = 0.0f;
        if (k != 0) {
            unsigned idx = ~(unsigned)(k & 0xFFFFFFFFull);
            int xi = (int)(idx & (W - 1));
            int yi = (int)(idx >> 9);
            float offx = offs[((size_t)j * 2 + 0) * HW + idx];
            float offy = offs[((size_t)j * 2 + 1) * HW + idx];
            float sf = (float)(*stride_p);
            hx = __fmul_rn(sf, __fadd_rn((float)xi, offx));
            hy = __fmul_rn(sf, __fadd_rn((float)yi, offy));
        }
        heat_xy[(j * TOPK + t) * 2 + 0] = hx;
        heat_xy[(j * TOPK + t) * 2 + 1] = hy;
    }
}

// ---------------------------------------------------------------------------
// Shared epilogue helper: d^2 argmin with two-min tracking + sqrt certificate.
// m1 = min d2 (first index wins via strict <, matching jnp.argmin); m2 =
// second-min COUNTING duplicates (min/max/min network). Certificate: every
// other candidate has d2 >= m2; if sqrt_rn(m2) > sqrt_rn(m1) then no other
// candidate shares the reference's min sqrt -> d2-argmin == sqrt-argmin.
// Exact d2 duplicates give m2==m1 -> certificate fires -> exact fallback
// scan (bitwise reference semantics). sqrt_rn monotone non-decreasing.
// ---------------------------------------------------------------------------
static __device__ __forceinline__ float2 snap_finish(const float2* __restrict__ cj,
                                                     float m1, float m2, int bk,
                                                     float2 p)
{
    float smin = __fsqrt_rn(m1);
    if (__fsqrt_rn(m2) == smin) {
        float bs = INFINITY; bk = 0;
        for (int k = 0; k < TOPK; ++k) {
            float2 c  = cj[k];
            float  dx = __fsub_rn(p.x, c.x);
            float  dy = __fsub_rn(p.y, c.y);
            float  s  = __fsqrt_rn(__fadd_rn(__fmul_rn(dx, dx), __fmul_rn(dy, dy)));
            if (s < bs) { bs = s; bk = k; }
        }
    }
    return cj[bk];
}

// ---------------------------------------------------------------------------
// K3 (P=4): nearest-candidate snap, 4 pose-joints per thread sharing one
// joint. Thread tid handles flat indices tid, tid+Q, tid+2Q, tid+3Q with
// Q = NJ/4; Q % 17 == 0 so all four share j = tid % 17 -> ONE ds_read_b64
// per candidate feeds 4 distance evals (DS-pipe was the K3 bottleneck:
// ~104 waves/CU x 30 reads x ~7cy ~ 9us serial on the per-CU DS pipe; /4
// makes K3 VALU-bound ~7us). cand row stride 33: bank=(2j+2k)%32 -> max
// 2-way conflict (free, m136) vs 3-way at stride 30. All global loads and
// stores stay coalesced (constant offset Q between streams). Update chain
// slimmed to cmp/cndmask/min/max/min (5 ops) via two-min tracking.
// ---------------------------------------------------------------------------
__global__ __launch_bounds__(256) void assign_nearest4(const float2* __restrict__ poses,
                                                       const float2* __restrict__ hxy,
                                                       float2* __restrict__ out,
                                                       int NJ)
{
    __shared__ float2 cand[NJOINT * CSTRIDE];
    const int t = threadIdx.x;
    for (int i = t; i < NJOINT * TOPK; i += 256) cand[(i / TOPK) * CSTRIDE + (i % TOPK)] = hxy[i];
    __syncthreads();
    const int Q = NJ >> 2;                 // launcher guarantees NJ % (4*17) == 0
    int tid = blockIdx.x * 256 + t;
    if (tid >= Q) return;
    const int j = tid % NJOINT;            // identical for all 4 streams (Q % 17 == 0)
    const float2* cj = &cand[j * CSTRIDE];
    float2 p0 = poses[tid];
    float2 p1 = poses[tid + Q];
    float2 p2 = poses[tid + 2 * Q];
    float2 p3 = poses[tid + 3 * Q];
    float m10 = INFINITY, m20 = INFINITY; int bk0 = 0;
    float m11 = INFINITY, m21 = INFINITY; int bk1 = 0;
    float m12 = INFINITY, m22 = INFINITY; int bk2 = 0;
    float m13 = INFINITY, m23 = INFINITY; int bk3 = 0;
    #pragma unroll
    for (int k = 0; k < TOPK; ++k) {
        float2 c = cj[k];
        {
            float dx = __fsub_rn(p0.x, c.x), dy = __fsub_rn(p0.y, c.y);
            float d2 = __fadd_rn(__fmul_rn(dx, dx), __fmul_rn(dy, dy));
            bool lt = d2 < m10;                 // vs OLD m1 (first-index strict <)
            float hi = fmaxf(m10, d2);
            m10 = fminf(m10, d2);
            m20 = fminf(m20, hi);
            if (lt) bk0 = k;
        }
        {
            float dx = __fsub_rn(p1.x, c.x), dy = __fsub_rn(p1.y, c.y);
            float d2 = __fadd_rn(__fmul_rn(dx, dx), __fmul_rn(dy, dy));
            bool lt = d2 < m11;
            float hi = fmaxf(m11, d2);
            m11 = fminf(m11, d2);
            m21 = fminf(m21, hi);
            if (lt) bk1 = k;
        }
        {
            float dx = __fsub_rn(p2.x, c.x), dy = __fsub_rn(p2.y, c.y);
            float d2 = __fadd_rn(__fmul_rn(dx, dx), __fmul_rn(dy, dy));
            bool lt = d2 < m12;
            float hi = fmaxf(m12, d2);
            m12 = fminf(m12, d2);
            m22 = fminf(m22, hi);
            if (lt) bk2 = k;
        }
        {
            float dx = __fsub_rn(p3.x, c.x), dy = __fsub_rn(p3.y, c.y);
            float d2 = __fadd_rn(__fmul_rn(dx, dx), __fmul_rn(dy, dy));
            bool lt = d2 < m13;
            float hi = fmaxf(m13, d2);
            m13 = fminf(m13, d2);
            m23 = fminf(m23, hi);
            if (lt) bk3 = k;
        }
    }
    out[tid]         = snap_finish(cj, m10, m20, bk0, p0);
    out[tid + Q]     = snap_finish(cj, m11, m21, bk1, p1);
    out[tid + 2 * Q] = snap_finish(cj, m12, m22, bk2, p2);
    out[tid + 3 * Q] = snap_finish(cj, m13, m23, bk3, p3);
}

// ---------------------------------------------------------------------------
// K3 (P=1) generality fallback — only launched if NJ % (4*NJOINT) != 0
// (never for this problem's shapes). Same two-min + certificate scheme.
// ---------------------------------------------------------------------------
__global__ __launch_bounds__(256) void assign_nearest(const float2* __restrict__ poses,
                                                      const float2* __restrict__ hxy,
                                                      float2* __restrict__ out,
                                                      int NJ)
{
    __shared__ float2 cand[NJOINT * CSTRIDE];
    const int t = threadIdx.x;
    for (int i = t; i < NJOINT * TOPK; i += 256) cand[(i / TOPK) * CSTRIDE + (i % TOPK)] = hxy[i];
    __syncthreads();
    int tid = blockIdx.x * 256 + t;
    if (tid >= NJ) return;
    int j = tid % NJOINT;
    const float2* cj = &cand[j * CSTRIDE];
    float2 p = poses[tid];
    float m1 = INFINITY, m2 = INFINITY; int bk = 0;
    #pragma unroll
    for (int k = 0; k < TOPK; ++k) {
        float2 c  = cj[k];
        float  dx = __fsub_rn(p.x, c.x), dy = __fsub_rn(p.y, c.y);
        float  d2 = __fadd_rn(__fmul_rn(dx, dx), __fmul_rn(dy, dy));
        bool lt = d2 < m1;
        float hi = fmaxf(m1, d2);
        m1 = fminf(m1, d2);
        m2 = fminf(m2, hi);
        if (lt) bk = k;
    }
    out[tid] = snap_finish(cj, m1, m2, bk, p);
}

extern "C" void kernel_launch(void* const* d_in, const int* in_sizes, int n_in,
                              void* d_out, int out_size, void* d_ws, size_t ws_size,
                              hipStream_t stream)
{
    const float* poses    = (const float*)d_in[0];   // (N, 34)
    const float* heat     = (const float*)d_in[1];   // (17, 512, 512)
    const float* offs     = (const float*)d_in[2];   // (17, 2, 512, 512)
    const int*   stride_p = (const int*)d_in[3];     // scalar 4

    char* ws = (char*)d_ws;
    u64*   buf     = (u64*)ws;                                   // 17*512*8   = 69,632 B
    int*   flags   = (int*)(ws + (size_t)NJOINT * JCAP * 8);     // 17*32*4    = 2,176 B
    float* heat_xy = (float*)(ws + (size_t)NJOINT * JCAP * 8 + NJOINT * NSLAB * 4); // 4,080 B
    u64*   fb      = (u64*)(ws + (1 << 20));                     // fallback scratch @1 MiB, 35.7 MB

    dim3 g1(NSLAB, NJOINT, 1);
    nms_collect<<<g1, 256, 0, stream>>>(heat, buf, flags);

    topk_sort<<<NJOINT, 256, 0, stream>>>(buf, flags, heat, offs, stride_p, fb, heat_xy);

    int NJ = (in_sizes[0] / (2 * NJOINT)) * NJOINT;  // 100000 * 17
    if (NJ % (4 * NJOINT) == 0) {
        int Q = NJ / 4;
        assign_nearest4<<<(Q + 255) / 256, 256, 0, stream>>>(
            (const float2*)poses, (const float2*)heat_xy, (float2*)d_out, NJ);
    } else {
        assign_nearest<<<(NJ + 255) / 256, 256, 0, stream>>>(
            (const float2*)poses, (const float2*)heat_xy, (float2*)d_out, NJ);
    }
}